// Round 2
// baseline (192.047 us; speedup 1.0000x reference)
//
#include <hip/hip_runtime.h>
#include <hip/hip_bf16.h>

// B=8, T=2048, C=1024, H=64 single-head causal attention. f32 in, f32 out.
// Round 11: attn occupancy fix. Block = one (qt, slice, b) output tile; its 4
// waves each take a QUARTER of the kt range with private online-softmax state,
// merged once at the end via LDS (exact in exp2 domain). Grid 1024 blocks =
// 4 blocks/CU = 16 waves/CU (was 1 block/CU, 4 waves, 5.6% occupancy).
// LPT dispatch order (big qt first). qkv/transpose_w unchanged from round 10.
// Region map: region rt (0..1023) = 16 token rows, bf16[rt*32768 ..) inside
// those rows' consumed f32 input bytes. Q[t][h]@0, K[t][h]@1024, V^T[h][t16]@2048.

typedef __bf16 bf16;
typedef __bf16 bf16x8 __attribute__((ext_vector_type(8)));
typedef float f32x4 __attribute__((ext_vector_type(4)));
typedef unsigned int u32;
typedef u32 u32x2 __attribute__((ext_vector_type(2)));
typedef u32 u32x4 __attribute__((ext_vector_type(4)));

#define T_SZ 2048
#define C_SZ 1024
#define H_SZ 64
#define REGSZ 32768
#define QOFF 0
#define KOFF 1024
#define VOFF 2048
#define PPITCH 72
#define APITCH 1032   // 1024+8: rows 16B-aligned (2064B=129*16); b128 bank-uniform
#define NEG_BIG (-30000.0f)
#define QSCALE 0.04508422f  // (1/32) * log2(e)

__device__ __forceinline__ bf16x8 ld8(const bf16* p) { return *(const bf16x8*)p; }

// DPP rotate within 16-lane row. ROW_ROR:n = 0x120|n.
template <int CTRL>
__device__ __forceinline__ float dpp_mov(float x) {
  return __builtin_bit_cast(float,
      __builtin_amdgcn_update_dpp(0, __builtin_bit_cast(int, x), CTRL, 0xf, 0xf, true));
}
__device__ __forceinline__ float qmax16(float x) {
  x = fmaxf(x, dpp_mov<0x121>(x));
  x = fmaxf(x, dpp_mov<0x122>(x));
  x = fmaxf(x, dpp_mov<0x124>(x));
  x = fmaxf(x, dpp_mov<0x128>(x));
  return x;
}
__device__ __forceinline__ float qsum16(float x) {
  x += dpp_mov<0x121>(x);
  x += dpp_mov<0x122>(x);
  x += dpp_mov<0x124>(x);
  x += dpp_mov<0x128>(x);
  return x;
}

// ---------------------------------------------------------------------------
// Wt[mat][h][c] = W[mat][c][h] (bf16); QSCALE folded into Wq.
__global__ __launch_bounds__(256) void transpose_w(const float* __restrict__ Wq,
                                                   const float* __restrict__ Wk,
                                                   const float* __restrict__ Wv,
                                                   bf16* __restrict__ Wt) {
  __shared__ float sh[64][65];
  int ct = blockIdx.x;
  int mat = blockIdx.y;
  const float* W = (mat == 0) ? Wq : (mat == 1 ? Wk : Wv);
  int tid = threadIdx.x;
  int r = tid >> 2, cb = (tid & 3) * 16;

  const f32x4* src = (const f32x4*)(W + (size_t)(ct * 64 + r) * H_SZ + cb);
#pragma unroll
  for (int v = 0; v < 4; ++v) {
    f32x4 x = src[v];
#pragma unroll
    for (int j = 0; j < 4; ++j) sh[r][cb + v * 4 + j] = x[j];
  }
  __syncthreads();

  float scale = (mat == 0) ? QSCALE : 1.0f;
  bf16x8 o0, o1;
#pragma unroll
  for (int j = 0; j < 8; ++j) o0[j] = (bf16)(sh[cb + j][r] * scale);
#pragma unroll
  for (int j = 0; j < 8; ++j) o1[j] = (bf16)(sh[cb + 8 + j][r] * scale);
  bf16* dst = Wt + ((size_t)mat * H_SZ + r) * C_SZ + ct * 64 + cb;
  *(bf16x8*)dst = o0;
  *(bf16x8*)(dst + 8) = o1;
}

// ---------------------------------------------------------------------------
// QKV: 512 blocks x 256 thr (4 waves x 48 cols), 2 blocks/CU, M=32 tokens.
// Phase 1: stage 32x1024 f32 -> bf16 LDS, one full 4KB row per load instr.
// Phase 2: 32 K-iters; per iter per wave: 2 LDS df + 3 L2 wf + 6 MFMA —
// each wf feeds 2 MFMAs (row-groups).
//   Q/K tiles: mfma(wf, df) -> D[h][t];  V tiles: mfma(df, wf) -> D[t][h].
// -> every epilogue store is a packed 8B store. data/arena alias.
__global__ __launch_bounds__(256, 2) void qkv(const float* data, const bf16* __restrict__ Wt,
                                              bf16* arena) {
  __shared__ bf16 As[32 * APITCH];
  int blk = blockIdx.x;
  int tid = threadIdx.x;
  int w = tid >> 6, lane = tid & 63;
  int l15 = lane & 15, quad = lane >> 4;

  const float* src = data + (size_t)blk * 32 * C_SZ;
#pragma unroll
  for (int g = 0; g < 4; ++g) {
    f32x4 st[8];
#pragma unroll
    for (int i = 0; i < 8; ++i) {
      int row = g * 8 + i;
      st[i] = *(const f32x4*)(src + (size_t)row * C_SZ + tid * 4);
    }
#pragma unroll
    for (int i = 0; i < 8; ++i) {
      int row = g * 8 + i;
      bf16 t4[4] = {(bf16)st[i][0], (bf16)st[i][1], (bf16)st[i][2], (bf16)st[i][3]};
      *(u32x2*)(As + row * APITCH + tid * 4) = *(const u32x2*)t4;
    }
  }
  __syncthreads();  // region f32 fully consumed; LDS visible

  f32x4 acc[2][3];
  f32x4 zero = {0.f, 0.f, 0.f, 0.f};
#pragma unroll
  for (int rg = 0; rg < 2; ++rg)
#pragma unroll
    for (int j = 0; j < 3; ++j) acc[rg][j] = zero;

#pragma unroll 4
  for (int kc = 0; kc < C_SZ; kc += 32) {
    bf16x8 df0 = ld8(As + l15 * APITCH + kc + quad * 8);
    bf16x8 df1 = ld8(As + (16 + l15) * APITCH + kc + quad * 8);
#pragma unroll
    for (int j = 0; j < 3; ++j) {
      int colb = w * 48 + j * 16;
      bf16x8 wf = ld8(Wt + (size_t)(colb + l15) * C_SZ + kc + quad * 8);
      if (colb < 128) {  // Q/K: swapped operands -> D[h][t]
        acc[0][j] = __builtin_amdgcn_mfma_f32_16x16x32_bf16(wf, df0, acc[0][j], 0, 0, 0);
        acc[1][j] = __builtin_amdgcn_mfma_f32_16x16x32_bf16(wf, df1, acc[1][j], 0, 0, 0);
      } else {           // V: D[t][h]
        acc[0][j] = __builtin_amdgcn_mfma_f32_16x16x32_bf16(df0, wf, acc[0][j], 0, 0, 0);
        acc[1][j] = __builtin_amdgcn_mfma_f32_16x16x32_bf16(df1, wf, acc[1][j], 0, 0, 0);
      }
    }
  }

#pragma unroll
  for (int rg = 0; rg < 2; ++rg) {
    bf16* reg = arena + (size_t)(blk * 2 + rg) * REGSZ;
#pragma unroll
    for (int j = 0; j < 3; ++j) {
      int colb = w * 48 + j * 16;
      bf16 p4[4] = {(bf16)acc[rg][j][0], (bf16)acc[rg][j][1], (bf16)acc[rg][j][2],
                    (bf16)acc[rg][j][3]};
      if (colb < 128) {
        int mat = colb >> 6;                  // 0=Q, 1=K (tiles are 16-aligned)
        int h = (colb & 63) + quad * 4;       // 4 consecutive h, t=l15
        bf16* dst = reg + (mat == 0 ? QOFF : KOFF) + l15 * 64 + h;
        *(u32x2*)dst = *(const u32x2*)p4;
      } else {
        int h = (colb - 128) + l15;           // V^T [h][t16], 4 consecutive t
        bf16* dst = reg + VOFF + h * 16 + quad * 4;
        *(u32x2*)dst = *(const u32x2*)p4;
      }
    }
  }
}

// ---------------------------------------------------------------------------
// Flash attention. Block = one (qt, slice, b) 16x64 output tile; 4 waves each
// own a QUARTER of kt in [0, qt], private (m,l,accO); one LDS merge at end.
// Grid (128, 8): u = blockIdx.x, slice = u&3, qt = 31-(u>>2) (LPT order).
// 4 blocks/CU -> 16 waves/CU. K prefetch + early V loads; DPP softmax in
// exp2 domain (log2e/32 folded into Wq); P-transpose via per-wave LDS slice.
__global__ __launch_bounds__(256, 4) void attn(const bf16* __restrict__ arena,
                                               float* __restrict__ out) {
  __shared__ bf16 Ps[4][16 * PPITCH];
  __shared__ f32x4 Mg[3][6][64];  // waves 1..3 dump {accO[0..3], m, l}
  int u = blockIdx.x;
  int b = blockIdx.y;
  int slice = u & 3;
  int qt = 31 - (u >> 2);
  int tid = threadIdx.x;
  int w = tid >> 6, lane = tid & 63;
  int l15 = lane & 15, quad = lane >> 4;

  const bf16* base = arena + (size_t)b * 128 * REGSZ;

  const bf16* qreg = base + (size_t)(qt * 4 + slice) * REGSZ + QOFF + l15 * 64;
  bf16x8 qf0 = ld8(qreg + quad * 8);
  bf16x8 qf1 = ld8(qreg + 32 + quad * 8);

  f32x4 accO[4];
  f32x4 zero = {0.f, 0.f, 0.f, 0.f};
#pragma unroll
  for (int nt = 0; nt < 4; ++nt) accO[nt] = zero;
  float m[4], l[4];
#pragma unroll
  for (int r = 0; r < 4; ++r) { m[r] = NEG_BIG; l[r] = 0.f; }

  int qrow_base = qt * 64 + slice * 16 + quad * 4;
  int vro = (quad >> 1);                 // V region sub-index
  int vco = (quad & 1) * 8;              // V in-row offset

  // this wave's kt quarter
  int q4 = (qt + 4) >> 2;                // ceil((qt+1)/4)
  int kbeg = w * q4;
  int kend = min((w + 1) * q4, qt + 1);  // may be empty (kbeg >= kend)

  bf16x8 kf[8];
#pragma unroll
  for (int nt = 0; nt < 4; ++nt) {       // preload K for kt=kbeg (addr always valid)
    const bf16* kp = base + (size_t)(kbeg * 4 + nt) * REGSZ + KOFF + l15 * 64 + quad * 8;
    kf[2 * nt] = ld8(kp);
    kf[2 * nt + 1] = ld8(kp + 32);
  }

  for (int kt = kbeg; kt < kend; ++kt) {
    // V for this tile (issue early; consumed after softmax)
    bf16x8 vf[8];
#pragma unroll
    for (int kh = 0; kh < 2; ++kh) {
#pragma unroll
      for (int nt = 0; nt < 4; ++nt) {
        const bf16* vp = base + (size_t)(kt * 4 + kh * 2 + vro) * REGSZ + VOFF +
                         (nt * 16 + l15) * 16 + vco;
        vf[kh * 4 + nt] = ld8(vp);
      }
    }
    // prefetch next K tile
    bf16x8 kn[8];
    if (kt + 1 < kend) {
#pragma unroll
      for (int nt = 0; nt < 4; ++nt) {
        const bf16* kp = base + (size_t)((kt + 1) * 4 + nt) * REGSZ + KOFF + l15 * 64 + quad * 8;
        kn[2 * nt] = ld8(kp);
        kn[2 * nt + 1] = ld8(kp + 32);
      }
    }

    f32x4 sA[4];
#pragma unroll
    for (int nt = 0; nt < 4; ++nt) sA[nt] = zero;
#pragma unroll
    for (int nt = 0; nt < 4; ++nt) {
      sA[nt] = __builtin_amdgcn_mfma_f32_16x16x32_bf16(qf0, kf[2 * nt], sA[nt], 0, 0, 0);
      sA[nt] = __builtin_amdgcn_mfma_f32_16x16x32_bf16(qf1, kf[2 * nt + 1], sA[nt], 0, 0, 0);
    }

    if (kt == qt) {  // causal mask on diagonal tile
#pragma unroll
      for (int nt = 0; nt < 4; ++nt) {
        int colg = kt * 64 + nt * 16 + l15;
#pragma unroll
        for (int r = 0; r < 4; ++r)
          if (colg > qrow_base + r) sA[nt][r] = NEG_BIG;
      }
    }

    float alpha[4];
#pragma unroll
    for (int r = 0; r < 4; ++r) {
      float mx = qmax16(fmaxf(fmaxf(sA[0][r], sA[1][r]), fmaxf(sA[2][r], sA[3][r])));
      float mnew = fmaxf(m[r], mx);
      alpha[r] = exp2f(m[r] - mnew);
      m[r] = mnew;
    }

    float rs[4] = {0.f, 0.f, 0.f, 0.f};
#pragma unroll
    for (int nt = 0; nt < 4; ++nt) {
#pragma unroll
      for (int r = 0; r < 4; ++r) {
        float p = exp2f(sA[nt][r] - m[r]);
        sA[nt][r] = p;
        rs[r] += p;
      }
    }
#pragma unroll
    for (int r = 0; r < 4; ++r) l[r] = l[r] * alpha[r] + qsum16(rs[r]);

    // P: C/D layout -> per-wave LDS -> A layout (same-wave RAW, lgkm-ordered)
#pragma unroll
    for (int nt = 0; nt < 4; ++nt) {
#pragma unroll
      for (int r = 0; r < 4; ++r)
        Ps[w][(quad * 4 + r) * PPITCH + nt * 16 + l15] = (bf16)sA[nt][r];
    }

#pragma unroll
    for (int nt = 0; nt < 4; ++nt) {
#pragma unroll
      for (int r = 0; r < 4; ++r) accO[nt][r] *= alpha[r];
    }
    bf16x8 pf0 = ld8((const bf16*)Ps[w] + l15 * PPITCH + quad * 8);
    bf16x8 pf1 = ld8((const bf16*)Ps[w] + l15 * PPITCH + 32 + quad * 8);
#pragma unroll
    for (int nt = 0; nt < 4; ++nt) {
      accO[nt] = __builtin_amdgcn_mfma_f32_16x16x32_bf16(pf0, vf[nt], accO[nt], 0, 0, 0);
      accO[nt] = __builtin_amdgcn_mfma_f32_16x16x32_bf16(pf1, vf[4 + nt], accO[nt], 0, 0, 0);
    }

#pragma unroll
    for (int i = 0; i < 8; ++i) kf[i] = kn[i];
  }

  // merge the 4 kt-quarter partials (exact: O* = sum_w O_w * 2^(m_w - m*))
  if (w > 0) {
#pragma unroll
    for (int nt = 0; nt < 4; ++nt) Mg[w - 1][nt][lane] = accO[nt];
    f32x4 mv = {m[0], m[1], m[2], m[3]};
    f32x4 lv = {l[0], l[1], l[2], l[3]};
    Mg[w - 1][4][lane] = mv;
    Mg[w - 1][5][lane] = lv;
  }
  __syncthreads();
  if (w == 0) {
#pragma unroll
    for (int wv = 0; wv < 3; ++wv) {
      f32x4 mo = Mg[wv][4][lane];
      f32x4 lo = Mg[wv][5][lane];
      f32x4 oo[4];
#pragma unroll
      for (int nt = 0; nt < 4; ++nt) oo[nt] = Mg[wv][nt][lane];
#pragma unroll
      for (int r = 0; r < 4; ++r) {
        float mnew = fmaxf(m[r], mo[r]);
        float a = exp2f(m[r] - mnew);
        float bs = exp2f(mo[r] - mnew);
        l[r] = l[r] * a + lo[r] * bs;
#pragma unroll
        for (int nt = 0; nt < 4; ++nt) accO[nt][r] = accO[nt][r] * a + oo[nt][r] * bs;
        m[r] = mnew;
      }
    }

    float inv[4];
#pragma unroll
    for (int r = 0; r < 4; ++r) inv[r] = 1.f / l[r];
#pragma unroll
    for (int nt = 0; nt < 4; ++nt) {
#pragma unroll
      for (int r = 0; r < 4; ++r) {
        int t = qt * 64 + slice * 16 + quad * 4 + r;
        int h = nt * 16 + l15;
        out[((size_t)b * T_SZ + t) * H_SZ + h] = accO[nt][r] * inv[r];
      }
    }
  }
}

// ---------------------------------------------------------------------------
extern "C" void kernel_launch(void* const* d_in, const int* in_sizes, int n_in,
                              void* d_out, int out_size, void* d_ws, size_t ws_size,
                              hipStream_t stream) {
  const float* data = (const float*)d_in[0];
  bf16* arena = (bf16*)d_in[0];   // per-region QKV over consumed input rows
  bf16* Wt = (bf16*)d_out;        // 384 KB staging; dead before attn overwrites

  transpose_w<<<dim3(16, 3), 256, 0, stream>>>((const float*)d_in[1],
                                               (const float*)d_in[2],
                                               (const float*)d_in[3], Wt);
  qkv<<<512, 256, 0, stream>>>(data, Wt, arena);
  attn<<<dim3(128, 8), 256, 0, stream>>>(arena, (float*)d_out);
}

// Round 3
// 148.804 us; speedup vs baseline: 1.2906x; 1.2906x over previous
//
#include <hip/hip_runtime.h>
#include <hip/hip_bf16.h>

// B=8, T=2048, C=1024, H=64 single-head causal attention. f32 in, f32 out.
// Round 12: attn de-spill. Round 11's (256,4) bound squeezed VGPRs to 64 and
// spilled the fragment arrays (WRITE_SIZE 4->58 MB = scratch). Loop rebuilt to
// fit 128 VGPRs naturally: no K prefetch (TLP at 16 waves/CU covers L2
// latency), V loaded as two 16-reg halves at consumption points. Plus b<->XCD
// pinning (b = blockIdx.x & 7) so each XCD's L2 holds exactly one batch's
// K/V/Q. Block = one (qt, slice, b) 16x64 tile; 4 waves own kt-quarters with
// private online-softmax state, one LDS merge at end. LPT dispatch order.
// qkv/transpose_w unchanged from round 10.
// Region map: region rt (0..1023) = 16 token rows, bf16[rt*32768 ..) inside
// those rows' consumed f32 input bytes. Q[t][h]@0, K[t][h]@1024, V^T[h][t16]@2048.

typedef __bf16 bf16;
typedef __bf16 bf16x8 __attribute__((ext_vector_type(8)));
typedef float f32x4 __attribute__((ext_vector_type(4)));
typedef unsigned int u32;
typedef u32 u32x2 __attribute__((ext_vector_type(2)));
typedef u32 u32x4 __attribute__((ext_vector_type(4)));

#define T_SZ 2048
#define C_SZ 1024
#define H_SZ 64
#define REGSZ 32768
#define QOFF 0
#define KOFF 1024
#define VOFF 2048
#define PPITCH 72
#define APITCH 1032   // 1024+8: rows 16B-aligned (2064B=129*16); b128 bank-uniform
#define NEG_BIG (-30000.0f)
#define QSCALE 0.04508422f  // (1/32) * log2(e)

__device__ __forceinline__ bf16x8 ld8(const bf16* p) { return *(const bf16x8*)p; }

// DPP rotate within 16-lane row. ROW_ROR:n = 0x120|n.
template <int CTRL>
__device__ __forceinline__ float dpp_mov(float x) {
  return __builtin_bit_cast(float,
      __builtin_amdgcn_update_dpp(0, __builtin_bit_cast(int, x), CTRL, 0xf, 0xf, true));
}
__device__ __forceinline__ float qmax16(float x) {
  x = fmaxf(x, dpp_mov<0x121>(x));
  x = fmaxf(x, dpp_mov<0x122>(x));
  x = fmaxf(x, dpp_mov<0x124>(x));
  x = fmaxf(x, dpp_mov<0x128>(x));
  return x;
}
__device__ __forceinline__ float qsum16(float x) {
  x += dpp_mov<0x121>(x);
  x += dpp_mov<0x122>(x);
  x += dpp_mov<0x124>(x);
  x += dpp_mov<0x128>(x);
  return x;
}

// ---------------------------------------------------------------------------
// Wt[mat][h][c] = W[mat][c][h] (bf16); QSCALE folded into Wq.
__global__ __launch_bounds__(256) void transpose_w(const float* __restrict__ Wq,
                                                   const float* __restrict__ Wk,
                                                   const float* __restrict__ Wv,
                                                   bf16* __restrict__ Wt) {
  __shared__ float sh[64][65];
  int ct = blockIdx.x;
  int mat = blockIdx.y;
  const float* W = (mat == 0) ? Wq : (mat == 1 ? Wk : Wv);
  int tid = threadIdx.x;
  int r = tid >> 2, cb = (tid & 3) * 16;

  const f32x4* src = (const f32x4*)(W + (size_t)(ct * 64 + r) * H_SZ + cb);
#pragma unroll
  for (int v = 0; v < 4; ++v) {
    f32x4 x = src[v];
#pragma unroll
    for (int j = 0; j < 4; ++j) sh[r][cb + v * 4 + j] = x[j];
  }
  __syncthreads();

  float scale = (mat == 0) ? QSCALE : 1.0f;
  bf16x8 o0, o1;
#pragma unroll
  for (int j = 0; j < 8; ++j) o0[j] = (bf16)(sh[cb + j][r] * scale);
#pragma unroll
  for (int j = 0; j < 8; ++j) o1[j] = (bf16)(sh[cb + 8 + j][r] * scale);
  bf16* dst = Wt + ((size_t)mat * H_SZ + r) * C_SZ + ct * 64 + cb;
  *(bf16x8*)dst = o0;
  *(bf16x8*)(dst + 8) = o1;
}

// ---------------------------------------------------------------------------
// QKV: 512 blocks x 256 thr (4 waves x 48 cols), 2 blocks/CU, M=32 tokens.
// Phase 1: stage 32x1024 f32 -> bf16 LDS, one full 4KB row per load instr.
// Phase 2: 32 K-iters; per iter per wave: 2 LDS df + 3 L2 wf + 6 MFMA —
// each wf feeds 2 MFMAs (row-groups).
//   Q/K tiles: mfma(wf, df) -> D[h][t];  V tiles: mfma(df, wf) -> D[t][h].
// -> every epilogue store is a packed 8B store. data/arena alias.
__global__ __launch_bounds__(256, 2) void qkv(const float* data, const bf16* __restrict__ Wt,
                                              bf16* arena) {
  __shared__ bf16 As[32 * APITCH];
  int blk = blockIdx.x;
  int tid = threadIdx.x;
  int w = tid >> 6, lane = tid & 63;
  int l15 = lane & 15, quad = lane >> 4;

  const float* src = data + (size_t)blk * 32 * C_SZ;
#pragma unroll
  for (int g = 0; g < 4; ++g) {
    f32x4 st[8];
#pragma unroll
    for (int i = 0; i < 8; ++i) {
      int row = g * 8 + i;
      st[i] = *(const f32x4*)(src + (size_t)row * C_SZ + tid * 4);
    }
#pragma unroll
    for (int i = 0; i < 8; ++i) {
      int row = g * 8 + i;
      bf16 t4[4] = {(bf16)st[i][0], (bf16)st[i][1], (bf16)st[i][2], (bf16)st[i][3]};
      *(u32x2*)(As + row * APITCH + tid * 4) = *(const u32x2*)t4;
    }
  }
  __syncthreads();  // region f32 fully consumed; LDS visible

  f32x4 acc[2][3];
  f32x4 zero = {0.f, 0.f, 0.f, 0.f};
#pragma unroll
  for (int rg = 0; rg < 2; ++rg)
#pragma unroll
    for (int j = 0; j < 3; ++j) acc[rg][j] = zero;

#pragma unroll 4
  for (int kc = 0; kc < C_SZ; kc += 32) {
    bf16x8 df0 = ld8(As + l15 * APITCH + kc + quad * 8);
    bf16x8 df1 = ld8(As + (16 + l15) * APITCH + kc + quad * 8);
#pragma unroll
    for (int j = 0; j < 3; ++j) {
      int colb = w * 48 + j * 16;
      bf16x8 wf = ld8(Wt + (size_t)(colb + l15) * C_SZ + kc + quad * 8);
      if (colb < 128) {  // Q/K: swapped operands -> D[h][t]
        acc[0][j] = __builtin_amdgcn_mfma_f32_16x16x32_bf16(wf, df0, acc[0][j], 0, 0, 0);
        acc[1][j] = __builtin_amdgcn_mfma_f32_16x16x32_bf16(wf, df1, acc[1][j], 0, 0, 0);
      } else {           // V: D[t][h]
        acc[0][j] = __builtin_amdgcn_mfma_f32_16x16x32_bf16(df0, wf, acc[0][j], 0, 0, 0);
        acc[1][j] = __builtin_amdgcn_mfma_f32_16x16x32_bf16(df1, wf, acc[1][j], 0, 0, 0);
      }
    }
  }

#pragma unroll
  for (int rg = 0; rg < 2; ++rg) {
    bf16* reg = arena + (size_t)(blk * 2 + rg) * REGSZ;
#pragma unroll
    for (int j = 0; j < 3; ++j) {
      int colb = w * 48 + j * 16;
      bf16 p4[4] = {(bf16)acc[rg][j][0], (bf16)acc[rg][j][1], (bf16)acc[rg][j][2],
                    (bf16)acc[rg][j][3]};
      if (colb < 128) {
        int mat = colb >> 6;                  // 0=Q, 1=K (tiles are 16-aligned)
        int h = (colb & 63) + quad * 4;       // 4 consecutive h, t=l15
        bf16* dst = reg + (mat == 0 ? QOFF : KOFF) + l15 * 64 + h;
        *(u32x2*)dst = *(const u32x2*)p4;
      } else {
        int h = (colb - 128) + l15;           // V^T [h][t16], 4 consecutive t
        bf16* dst = reg + VOFF + h * 16 + quad * 4;
        *(u32x2*)dst = *(const u32x2*)p4;
      }
    }
  }
}

// ---------------------------------------------------------------------------
// Flash attention. Block = one (qt, slice, b) 16x64 output tile; 4 waves each
// own a QUARTER of kt in [0, qt], private (m,l,accO); one LDS merge at end.
// Grid 1024 1-D: b = id&7 (pins batch b to XCD b under round-robin dispatch:
// that XCD's L2 then holds exactly one batch's K/V/Q, ~1.5 MB). t = id>>3,
// slice = t&3, qt = 31-(t>>2) (LPT order). 4 blocks/CU -> 16 waves/CU.
// Register budget: no K prefetch, V in two 16-reg halves -> peak ~110 VGPR,
// fits the (256,4) 128-reg budget with NO scratch (round 11 spilled: 58 MB
// phantom WRITE_SIZE). Latency hiding comes from 4 waves/SIMD TLP.
__global__ __launch_bounds__(256, 4) void attn(const bf16* __restrict__ arena,
                                               float* __restrict__ out) {
  __shared__ bf16 Ps[4][16 * PPITCH];
  __shared__ f32x4 Mg[3][6][64];  // waves 1..3 dump {accO[0..3], m, l}
  int id = blockIdx.x;
  int b = id & 7;
  int t = id >> 3;
  int slice = t & 3;
  int qt = 31 - (t >> 2);
  int tid = threadIdx.x;
  int w = tid >> 6, lane = tid & 63;
  int l15 = lane & 15, quad = lane >> 4;

  const bf16* base = arena + (size_t)b * 128 * REGSZ;

  const bf16* qreg = base + (size_t)(qt * 4 + slice) * REGSZ + QOFF + l15 * 64;
  bf16x8 qf0 = ld8(qreg + quad * 8);
  bf16x8 qf1 = ld8(qreg + 32 + quad * 8);

  f32x4 accO[4];
  f32x4 zero = {0.f, 0.f, 0.f, 0.f};
#pragma unroll
  for (int nt = 0; nt < 4; ++nt) accO[nt] = zero;
  float m[4], l[4];
#pragma unroll
  for (int r = 0; r < 4; ++r) { m[r] = NEG_BIG; l[r] = 0.f; }

  int qrow_base = qt * 64 + slice * 16 + quad * 4;
  int vro = (quad >> 1);                 // V region sub-index
  int vco = (quad & 1) * 8;              // V in-row offset

  // this wave's kt quarter
  int q4 = (qt + 4) >> 2;                // ceil((qt+1)/4)
  int kbeg = w * q4;
  int kend = min((w + 1) * q4, qt + 1);  // may be empty (kbeg >= kend)

  for (int kt = kbeg; kt < kend; ++kt) {
    // K fragments for this tile (L2-resident; TLP hides latency)
    bf16x8 kf[8];
#pragma unroll
    for (int nt = 0; nt < 4; ++nt) {
      const bf16* kp = base + (size_t)(kt * 4 + nt) * REGSZ + KOFF + l15 * 64 + quad * 8;
      kf[2 * nt] = ld8(kp);
      kf[2 * nt + 1] = ld8(kp + 32);
    }

    f32x4 sA[4];
#pragma unroll
    for (int nt = 0; nt < 4; ++nt) sA[nt] = zero;
#pragma unroll
    for (int nt = 0; nt < 4; ++nt) {
      sA[nt] = __builtin_amdgcn_mfma_f32_16x16x32_bf16(qf0, kf[2 * nt], sA[nt], 0, 0, 0);
      sA[nt] = __builtin_amdgcn_mfma_f32_16x16x32_bf16(qf1, kf[2 * nt + 1], sA[nt], 0, 0, 0);
    }

    // first V half: issue under the softmax (kf regs die at the MFMAs above)
    bf16x8 vf0[4];
#pragma unroll
    for (int nt = 0; nt < 4; ++nt) {
      const bf16* vp = base + (size_t)(kt * 4 + vro) * REGSZ + VOFF +
                       (nt * 16 + l15) * 16 + vco;
      vf0[nt] = ld8(vp);
    }

    if (kt == qt) {  // causal mask on diagonal tile
#pragma unroll
      for (int nt = 0; nt < 4; ++nt) {
        int colg = kt * 64 + nt * 16 + l15;
#pragma unroll
        for (int r = 0; r < 4; ++r)
          if (colg > qrow_base + r) sA[nt][r] = NEG_BIG;
      }
    }

    float alpha[4];
#pragma unroll
    for (int r = 0; r < 4; ++r) {
      float mx = qmax16(fmaxf(fmaxf(sA[0][r], sA[1][r]), fmaxf(sA[2][r], sA[3][r])));
      float mnew = fmaxf(m[r], mx);
      alpha[r] = exp2f(m[r] - mnew);
      m[r] = mnew;
    }

    float rs[4] = {0.f, 0.f, 0.f, 0.f};
#pragma unroll
    for (int nt = 0; nt < 4; ++nt) {
#pragma unroll
      for (int r = 0; r < 4; ++r) {
        float p = exp2f(sA[nt][r] - m[r]);
        sA[nt][r] = p;
        rs[r] += p;
      }
    }
#pragma unroll
    for (int r = 0; r < 4; ++r) l[r] = l[r] * alpha[r] + qsum16(rs[r]);

    // P: C/D layout -> per-wave LDS -> A layout (same-wave RAW, lgkm-ordered)
#pragma unroll
    for (int nt = 0; nt < 4; ++nt) {
#pragma unroll
      for (int r = 0; r < 4; ++r)
        Ps[w][(quad * 4 + r) * PPITCH + nt * 16 + l15] = (bf16)sA[nt][r];
    }

    // second V half: issue before PV so latency hides under first PV block
    bf16x8 vf1[4];
#pragma unroll
    for (int nt = 0; nt < 4; ++nt) {
      const bf16* vp = base + (size_t)(kt * 4 + 2 + vro) * REGSZ + VOFF +
                       (nt * 16 + l15) * 16 + vco;
      vf1[nt] = ld8(vp);
    }

#pragma unroll
    for (int nt = 0; nt < 4; ++nt) {
#pragma unroll
      for (int r = 0; r < 4; ++r) accO[nt][r] *= alpha[r];
    }
    bf16x8 pf0 = ld8((const bf16*)Ps[w] + l15 * PPITCH + quad * 8);
    bf16x8 pf1 = ld8((const bf16*)Ps[w] + l15 * PPITCH + 32 + quad * 8);
#pragma unroll
    for (int nt = 0; nt < 4; ++nt)
      accO[nt] = __builtin_amdgcn_mfma_f32_16x16x32_bf16(pf0, vf0[nt], accO[nt], 0, 0, 0);
#pragma unroll
    for (int nt = 0; nt < 4; ++nt)
      accO[nt] = __builtin_amdgcn_mfma_f32_16x16x32_bf16(pf1, vf1[nt], accO[nt], 0, 0, 0);
  }

  // merge the 4 kt-quarter partials (exact: O* = sum_w O_w * 2^(m_w - m*))
  if (w > 0) {
#pragma unroll
    for (int nt = 0; nt < 4; ++nt) Mg[w - 1][nt][lane] = accO[nt];
    f32x4 mv = {m[0], m[1], m[2], m[3]};
    f32x4 lv = {l[0], l[1], l[2], l[3]};
    Mg[w - 1][4][lane] = mv;
    Mg[w - 1][5][lane] = lv;
  }
  __syncthreads();
  if (w == 0) {
#pragma unroll
    for (int wv = 0; wv < 3; ++wv) {
      f32x4 mo = Mg[wv][4][lane];
      f32x4 lo = Mg[wv][5][lane];
      f32x4 oo[4];
#pragma unroll
      for (int nt = 0; nt < 4; ++nt) oo[nt] = Mg[wv][nt][lane];
#pragma unroll
      for (int r = 0; r < 4; ++r) {
        float mnew = fmaxf(m[r], mo[r]);
        float a = exp2f(m[r] - mnew);
        float bs = exp2f(mo[r] - mnew);
        l[r] = l[r] * a + lo[r] * bs;
#pragma unroll
        for (int nt = 0; nt < 4; ++nt) accO[nt][r] = accO[nt][r] * a + oo[nt][r] * bs;
        m[r] = mnew;
      }
    }

    float inv[4];
#pragma unroll
    for (int r = 0; r < 4; ++r) inv[r] = 1.f / l[r];
#pragma unroll
    for (int nt = 0; nt < 4; ++nt) {
#pragma unroll
      for (int r = 0; r < 4; ++r) {
        int tk = qt * 64 + slice * 16 + quad * 4 + r;
        int h = nt * 16 + l15;
        out[((size_t)b * T_SZ + tk) * H_SZ + h] = accO[nt][r] * inv[r];
      }
    }
  }
}

// ---------------------------------------------------------------------------
extern "C" void kernel_launch(void* const* d_in, const int* in_sizes, int n_in,
                              void* d_out, int out_size, void* d_ws, size_t ws_size,
                              hipStream_t stream) {
  const float* data = (const float*)d_in[0];
  bf16* arena = (bf16*)d_in[0];   // per-region QKV over consumed input rows
  bf16* Wt = (bf16*)d_out;        // 384 KB staging; dead before attn overwrites

  transpose_w<<<dim3(16, 3), 256, 0, stream>>>((const float*)d_in[1],
                                               (const float*)d_in[2],
                                               (const float*)d_in[3], Wt);
  qkv<<<512, 256, 0, stream>>>(data, Wt, arena);
  attn<<<1024, 256, 0, stream>>>(arena, (float*)d_out);
}